// Round 12
// baseline (148.071 us; speedup 1.0000x reference)
//
#include <hip/hip_runtime.h>

#define BIGF 1e30f
#define LOG2E 1.4426950408889634f
#define LN2F 0.6931471805599453f

constexpr int NB = 16;    // batches
constexpr int NN = 512;   // N rows
constexpr int MM = 512;   // M cols
constexpr int KD = 64;    // feature dim
constexpr int WAVES = 8;                     // 512 threads, 1 row/lane
constexpr int CSPAN = 32;                    // diagonals per barrier phase
constexpr int NSPANS = 32;                   // 1023 diagonals / 32
constexpr int SPW = 18;                      // spans per 64-row block
constexpr int TPH = 3 * (WAVES - 1) + SPW;   // 39 barrier phases
constexpr int DIAGELEMS = NN * MM;

// bbuf row covers columns [-62, 609] -> index = 62 + j, stride 672.
constexpr int BBSTRIDE = 672;
constexpr int BBUF_FLOATS = WAVES * BBSTRIDE;  // 5376 (21 KiB) — only LDS use

// Packed anti-diagonal layout: element (i,j) [0-based] lives at
// Dsk[b*DIAGELEMS + B(s) + i],  s = i+j.
__device__ __forceinline__ int Bclosed(int s) {
  return (s <= 511) ? (s * (s + 1)) / 2
                    : DIAGELEMS - ((1023 - s) * (1024 - s)) / 2 - (s - 511);
}

// ---------------- Kernel 1: pairwise squared distances (exp2-domain) -------
__global__ __launch_bounds__(256) void pairdist_kernel(
    const float* __restrict__ X, const float* __restrict__ Y,
    float* __restrict__ Dsk) {
  const int b = blockIdx.z;
  const int i0 = blockIdx.y * 64;
  const int j0 = blockIdx.x * 64;

  __shared__ float Xs[64][65];
  __shared__ float Ys[64][65];
  __shared__ float Ds[64][66];  // stride 66: diag reads (stride 65) conflict-free

  const float* Xb = X + ((size_t)b * NN + i0) * KD;
  const float* Yb = Y + ((size_t)b * MM + j0) * KD;
  for (int k = threadIdx.x; k < 64 * KD; k += 256) {
    Xs[k >> 6][k & 63] = Xb[k];
    Ys[k >> 6][k & 63] = Yb[k];
  }
  __syncthreads();

  const int tx = threadIdx.x & 15;
  const int ty = threadIdx.x >> 4;
  const int r0 = ty * 4, c0 = tx * 4;

  float acc[4][4];
#pragma unroll
  for (int a = 0; a < 4; ++a)
#pragma unroll
    for (int e = 0; e < 4; ++e) acc[a][e] = 0.0f;

  for (int d = 0; d < KD; ++d) {
    float xv[4], yv[4];
#pragma unroll
    for (int q = 0; q < 4; ++q) xv[q] = Xs[r0 + q][d];
#pragma unroll
    for (int q = 0; q < 4; ++q) yv[q] = Ys[c0 + q][d];
#pragma unroll
    for (int a = 0; a < 4; ++a)
#pragma unroll
      for (int e = 0; e < 4; ++e) {
        float df = xv[a] - yv[e];
        acc[a][e] = fmaf(df, df, acc[a][e]);
      }
  }

#pragma unroll
  for (int a = 0; a < 4; ++a)
#pragma unroll
    for (int e = 0; e < 4; ++e)
      Ds[r0 + a][c0 + e] = fminf(acc[a][e], 10000.0f) * LOG2E;
  __syncthreads();

  // diag-major coalesced stores: wave handles diag sl, 64 lanes = 1 segment
  const int wv = threadIdx.x >> 6;
  const int ln = threadIdx.x & 63;
  float* Db = Dsk + (size_t)b * DIAGELEMS;
  for (int sl = wv; sl < 127; sl += 4) {
    const int istart = sl > 63 ? sl - 63 : 0;
    const int iend = sl < 63 ? sl : 63;
    if (ln <= iend - istart) {
      const int ig = i0 + istart + ln;  // global row
      Db[Bclosed(i0 + j0 + sl) + ig] = Ds[istart + ln][sl - istart - ln];
    }
  }
}

// up1 = lane i-1's ra; lane 0 takes old[lane0] = B[lane0] (boundary inject).
__device__ __forceinline__ float dpp_shr1_old(float oldv, float v) {
  return __int_as_float(__builtin_amdgcn_update_dpp(
      __float_as_int(oldv), __float_as_int(v), 0x138 /*WAVE_SHR1*/, 0xf, 0xf,
      false));
}
// B[l] <- B[l+1] (advance boundary stream; high lanes keep junk).
__device__ __forceinline__ float dpp_shl1(float v) {
  return __int_as_float(__builtin_amdgcn_update_dpp(
      __float_as_int(v), __float_as_int(v), 0x130 /*WAVE_SHL1*/, 0xf, 0xf,
      false));
}

// Full-rate bit-hack exp2/log2 (Schraudolph, balanced bias 0.0450466).
__device__ __forceinline__ float fexp2(float x) {
  x = fmaxf(x, -126.0f);
  return __int_as_float((int)fmaf(x, 8388608.0f, 1.064975338e9f));
}
__device__ __forceinline__ float flog2(float y) {
  return fmaf((float)__float_as_int(y), 1.1920929e-7f, -126.9549534f);
}

// Load one span's 32 D values for this lane's row straight into registers.
// Wave-level: per step k the 64 lanes read a contiguous 256B segment
// (coalesced). Base index walks the packed-diag prefix sum in SALU.
#define FILL(ARR, Q)                                                        \
  do {                                                                      \
    const int q_ = (Q);                                                     \
    int s0_ = 32 * q_;                                                      \
    int idx_ = Bclosed(s0_ > 1022 ? 1022 : s0_);                            \
    _Pragma("unroll") for (int k_ = 0; k_ < CSPAN; ++k_) {                  \
      const int s_ = 32 * q_ + k_;                                          \
      int e_ = idx_ + r;                                                    \
      e_ = e_ > DIAGELEMS - 1 ? DIAGELEMS - 1 : e_;                         \
      ARR[k_] = Du[e_];                                                     \
      idx_ += (s_ < 511) ? s_ + 1 : ((s_ < 1022) ? 1022 - s_ : 0);          \
    }                                                                       \
  } while (0)

#define SOFTMIN_STEP(DVK)                                                   \
  {                                                                         \
    const float up1 = dpp_shr1_old(B, ra);                                  \
    B = dpp_shl1(B);                                                        \
    const float m = fminf(fminf(up1, up2), ra);                             \
    const float md = __builtin_amdgcn_fmed3f(up1, up2, ra);                 \
    const float mx = fmaxf(fmaxf(up1, up2), ra);                            \
    const float ssum = (fexp2(m - md) + fexp2(m - mx)) + 1.0f;              \
    n = ((DVK) + m) - flog2(ssum);                                          \
    up2 = up1;                                                              \
  }

#define PHASE(DVC, DVN)                                                     \
  do {                                                                      \
    if (cc + 1 < SPW) FILL(DVN, c + 1); /* issue-early, consume next phase */ \
    float B = BIGF;                                                         \
    if (blk) B = bbuf[blk * BBSTRIDE + 62 + 32 * cc + 1 + lane];            \
    float* pubp =                                                           \
        bbuf + ((blk + 1) & 7) * BBSTRIDE + (62 + 32 * c - r + 1);          \
    float n;                                                                \
    if (cc >= 2 && cc <= 15) { /* all 64 lanes active at all 32 steps */    \
      _Pragma("unroll") for (int k = 0; k < CSPAN; ++k) {                   \
        SOFTMIN_STEP(DVC[k]);                                               \
        ra = n;                                                             \
        pubp[k] = ra;                                                       \
      }                                                                     \
    } else { /* edge phases: keep activity mask */                          \
      const int jv0 = 32 * c - r + 1;                                       \
      _Pragma("unroll") for (int k = 0; k < CSPAN; ++k) {                   \
        SOFTMIN_STEP(DVC[k]);                                               \
        const bool a0 = (unsigned)(jv0 + k - 1) < (unsigned)MM;             \
        ra = a0 ? n : ra;                                                   \
        pubp[k] = ra;                                                       \
      }                                                                     \
    }                                                                       \
  } while (0)

// ---------------- Kernel 2: soft-DTW wavefront DP (base-2 domain) ----------
// One block per batch, 8 waves x 64 lanes, 1 row per lane (2 waves/SIMD).
// D values: global -> register double-buffer (dvA/dvB), coalesced, issued a
// full phase ahead. LDS pipe carries ONLY the boundary handoff (1 read +
// 32 writes per wave per phase) — the previous structure's 73 DS ops/wave
// (mega-asm reads + DMA LDS-write returns) were the per-CU DS-pipe wall.
__global__ __launch_bounds__(512) void softdtw_kernel(
    const float* __restrict__ Dsk, float* __restrict__ out) {
  const int b = blockIdx.x;
  const int t = threadIdx.x;
  const int wu = __builtin_amdgcn_readfirstlane(t >> 6);
  const int lane = t & 63;
  const int blk = ((wu & 3) << 1) | (wu >> 2);  // row-block 0..7

  __shared__ float bbuf[BBUF_FLOATS];  // [8][672]: row w col j at [w][62+j]

  for (int k = t; k < BBUF_FLOATS; k += 512) bbuf[k] = BIGF;
  __syncthreads();

  const float* __restrict__ Du = Dsk + (size_t)b * DIAGELEMS;
  const int r = 64 * blk + lane;  // 0-based row; cell row i = r+1

  float dvA[CSPAN], dvB[CSPAN];
  FILL(dvA, 2 * blk);  // first span; consumed at phase 3*blk (latency hidden)

  float ra = BIGF;  // R'[i][j-1]
  // up2 = R'[i-1][j-1] = previous step's up1; seed R'[0][0]=0 for the origin.
  float up2 = (blk == 0 && lane == 0) ? 0.0f : BIGF;

  for (int S = 0; S < TPH; ++S) {
    const int cc = S - 3 * blk;  // phase-local span index
    if (cc >= 0 && cc < SPW) {
      const int c = cc + 2 * blk;  // global span (<= 31)
      if (cc & 1) {
        PHASE(dvB, dvA);
      } else {
        PHASE(dvA, dvB);
      }
    }
    // Raw barrier: drain LDS ops only (bbuf publish visibility). The dv
    // prefetch loads stay in flight across the barrier; the "memory"
    // clobber bounds compiler motion of the FILL loads.
    asm volatile("s_waitcnt lgkmcnt(0)" ::: "memory");
    __builtin_amdgcn_s_barrier();
  }

  if (blk == WAVES - 1 && lane == 63) out[b] = ra * LN2F;  // R'[512][512]
}

extern "C" void kernel_launch(void* const* d_in, const int* in_sizes, int n_in,
                              void* d_out, int out_size, void* d_ws,
                              size_t ws_size, hipStream_t stream) {
  const float* X = (const float*)d_in[0];
  const float* Y = (const float*)d_in[1];
  float* out = (float*)d_out;
  float* Dsk = (float*)d_ws;

  const size_t needed = (size_t)NB * DIAGELEMS * sizeof(float);
  if (ws_size < needed) return;

  pairdist_kernel<<<dim3(MM / 64, NN / 64, NB), 256, 0, stream>>>(X, Y, Dsk);
  softdtw_kernel<<<NB, 512, 0, stream>>>(Dsk, out);
}

// Round 13
// 145.461 us; speedup vs baseline: 1.0179x; 1.0179x over previous
//
#include <hip/hip_runtime.h>

#define BIGF 1e30f
#define LOG2E 1.4426950408889634f
#define LN2F 0.6931471805599453f

constexpr int NB = 16;    // batches
constexpr int NN = 512;   // N rows
constexpr int MM = 512;   // M cols
constexpr int KD = 64;    // feature dim
constexpr int WAVES = 8;                     // 512 threads, 1 row/lane
constexpr int CSPAN = 64;                    // diagonals per barrier phase
constexpr int NSPANS = 16;                   // 1023 diagonals / 64
constexpr int SPW = 9;                       // spans per 64-row block
constexpr int OFF = 2;                       // phase skew between blocks
constexpr int TPH = OFF * (WAVES - 1) + SPW; // 23 barrier phases
constexpr int DIAGELEMS = NN * MM;

// bbuf row covers columns [-62, 577] -> index = 62 + j, stride 640.
constexpr int BBSTRIDE = 640;
constexpr int BUFD_FLOATS = WAVES * CSPAN * 64;   // 32768 (128 KiB, 1 buf/blk)
constexpr int BBUF_FLOATS = WAVES * BBSTRIDE;     // 5120  (20 KiB)
constexpr int SMEM_BYTES = (BUFD_FLOATS + BBUF_FLOATS) * 4;  // 151552

// Packed anti-diagonal layout: element (i,j) [0-based] lives at
// Dsk[b*DIAGELEMS + B(s) + i],  s = i+j.
__device__ __forceinline__ int Bclosed(int s) {
  return (s <= 511) ? (s * (s + 1)) / 2
                    : DIAGELEMS - ((1023 - s) * (1024 - s)) / 2 - (s - 511);
}

// ---------------- Kernel 1: pairwise squared distances (exp2-domain) -------
__global__ __launch_bounds__(256) void pairdist_kernel(
    const float* __restrict__ X, const float* __restrict__ Y,
    float* __restrict__ Dsk) {
  const int b = blockIdx.z;
  const int i0 = blockIdx.y * 64;
  const int j0 = blockIdx.x * 64;

  __shared__ float Xs[64][65];
  __shared__ float Ys[64][65];
  __shared__ float Ds[64][66];  // stride 66: diag reads (stride 65) conflict-free

  const float* Xb = X + ((size_t)b * NN + i0) * KD;
  const float* Yb = Y + ((size_t)b * MM + j0) * KD;
  for (int k = threadIdx.x; k < 64 * KD; k += 256) {
    Xs[k >> 6][k & 63] = Xb[k];
    Ys[k >> 6][k & 63] = Yb[k];
  }
  __syncthreads();

  const int tx = threadIdx.x & 15;
  const int ty = threadIdx.x >> 4;
  const int r0 = ty * 4, c0 = tx * 4;

  float acc[4][4];
#pragma unroll
  for (int a = 0; a < 4; ++a)
#pragma unroll
    for (int e = 0; e < 4; ++e) acc[a][e] = 0.0f;

  for (int d = 0; d < KD; ++d) {
    float xv[4], yv[4];
#pragma unroll
    for (int q = 0; q < 4; ++q) xv[q] = Xs[r0 + q][d];
#pragma unroll
    for (int q = 0; q < 4; ++q) yv[q] = Ys[c0 + q][d];
#pragma unroll
    for (int a = 0; a < 4; ++a)
#pragma unroll
      for (int e = 0; e < 4; ++e) {
        float df = xv[a] - yv[e];
        acc[a][e] = fmaf(df, df, acc[a][e]);
      }
  }

#pragma unroll
  for (int a = 0; a < 4; ++a)
#pragma unroll
    for (int e = 0; e < 4; ++e)
      Ds[r0 + a][c0 + e] = fminf(acc[a][e], 10000.0f) * LOG2E;
  __syncthreads();

  // diag-major coalesced stores: wave handles diag sl, 64 lanes = 1 segment
  const int wv = threadIdx.x >> 6;
  const int ln = threadIdx.x & 63;
  float* Db = Dsk + (size_t)b * DIAGELEMS;
  for (int sl = wv; sl < 127; sl += 4) {
    const int istart = sl > 63 ? sl - 63 : 0;
    const int iend = sl < 63 ? sl : 63;
    if (ln <= iend - istart) {
      const int ig = i0 + istart + ln;  // global row
      Db[Bclosed(i0 + j0 + sl) + ig] = Ds[istart + ln][sl - istart - ln];
    }
  }
}

// up1 = lane i-1's ra; lane 0 takes old[lane0] = B[lane0] (boundary inject).
__device__ __forceinline__ float dpp_shr1_old(float oldv, float v) {
  return __int_as_float(__builtin_amdgcn_update_dpp(
      __float_as_int(oldv), __float_as_int(v), 0x138 /*WAVE_SHR1*/, 0xf, 0xf,
      false));
}
// B[l] <- B[l+1] (advance boundary stream; high lanes keep junk).
__device__ __forceinline__ float dpp_shl1(float v) {
  return __int_as_float(__builtin_amdgcn_update_dpp(
      __float_as_int(v), __float_as_int(v), 0x130 /*WAVE_SHL1*/, 0xf, 0xf,
      false));
}

// Full-rate bit-hack exp2/log2 (Schraudolph, balanced bias 0.0450466).
__device__ __forceinline__ float fexp2(float x) {
  x = fmaxf(x, -126.0f);
  return __int_as_float((int)fmaf(x, 8388608.0f, 1.064975338e9f));
}
__device__ __forceinline__ float flog2(float y) {
  return fmaf((float)__float_as_int(y), 1.1920929e-7f, -126.9549534f);
}

// DMA one span's D-block (64 steps x 64 rows = 16 KiB) for row-block blk
// into its (single) LDS buffer. 16 x global_load_lds width-16.
__device__ __forceinline__ void dma_span(const float* __restrict__ Dskb,
                                         float* bufD, int blk, int q,
                                         int lane) {
  float* dst0 = bufD + blk * (CSPAN * 64);
  const int rbase = 64 * blk + (lane & 15) * 4;
  const int sub = lane >> 4;
#pragma unroll
  for (int u = 0; u < 16; ++u) {
    int s = 64 * q + 4 * u + sub;
    s = s > 1022 ? 1022 : s;
    int e = Bclosed(s) + rbase;
    e = e > DIAGELEMS - 4 ? DIAGELEMS - 4 : e;  // junk rows masked later
    __builtin_amdgcn_global_load_lds(
        (const __attribute__((address_space(1))) void*)(Dskb + e),
        (__attribute__((address_space(3))) void*)(dst0 + u * 256), 16, 0, 0);
  }
}

// 32 ds_read_b32 from ADDR (+k*256B) into DV[0..31]; TAIL appended.
#define DS_READ32(DV, ADDR, TAIL)                                           \
  asm volatile(                                                             \
      "ds_read_b32 %0, %32 offset:0\n\t"                                    \
      "ds_read_b32 %1, %32 offset:256\n\t"                                  \
      "ds_read_b32 %2, %32 offset:512\n\t"                                  \
      "ds_read_b32 %3, %32 offset:768\n\t"                                  \
      "ds_read_b32 %4, %32 offset:1024\n\t"                                 \
      "ds_read_b32 %5, %32 offset:1280\n\t"                                 \
      "ds_read_b32 %6, %32 offset:1536\n\t"                                 \
      "ds_read_b32 %7, %32 offset:1792\n\t"                                 \
      "ds_read_b32 %8, %32 offset:2048\n\t"                                 \
      "ds_read_b32 %9, %32 offset:2304\n\t"                                 \
      "ds_read_b32 %10, %32 offset:2560\n\t"                                \
      "ds_read_b32 %11, %32 offset:2816\n\t"                                \
      "ds_read_b32 %12, %32 offset:3072\n\t"                                \
      "ds_read_b32 %13, %32 offset:3328\n\t"                                \
      "ds_read_b32 %14, %32 offset:3584\n\t"                                \
      "ds_read_b32 %15, %32 offset:3840\n\t"                                \
      "ds_read_b32 %16, %32 offset:4096\n\t"                                \
      "ds_read_b32 %17, %32 offset:4352\n\t"                                \
      "ds_read_b32 %18, %32 offset:4608\n\t"                                \
      "ds_read_b32 %19, %32 offset:4864\n\t"                                \
      "ds_read_b32 %20, %32 offset:5120\n\t"                                \
      "ds_read_b32 %21, %32 offset:5376\n\t"                                \
      "ds_read_b32 %22, %32 offset:5632\n\t"                                \
      "ds_read_b32 %23, %32 offset:5888\n\t"                                \
      "ds_read_b32 %24, %32 offset:6144\n\t"                                \
      "ds_read_b32 %25, %32 offset:6400\n\t"                                \
      "ds_read_b32 %26, %32 offset:6656\n\t"                                \
      "ds_read_b32 %27, %32 offset:6912\n\t"                                \
      "ds_read_b32 %28, %32 offset:7168\n\t"                                \
      "ds_read_b32 %29, %32 offset:7424\n\t"                                \
      "ds_read_b32 %30, %32 offset:7680\n\t"                                \
      "ds_read_b32 %31, %32 offset:7936\n\t" TAIL                           \
      : "=&v"(DV[0]), "=&v"(DV[1]), "=&v"(DV[2]), "=&v"(DV[3]),             \
        "=&v"(DV[4]), "=&v"(DV[5]), "=&v"(DV[6]), "=&v"(DV[7]),             \
        "=&v"(DV[8]), "=&v"(DV[9]), "=&v"(DV[10]), "=&v"(DV[11]),           \
        "=&v"(DV[12]), "=&v"(DV[13]), "=&v"(DV[14]), "=&v"(DV[15]),         \
        "=&v"(DV[16]), "=&v"(DV[17]), "=&v"(DV[18]), "=&v"(DV[19]),         \
        "=&v"(DV[20]), "=&v"(DV[21]), "=&v"(DV[22]), "=&v"(DV[23]),         \
        "=&v"(DV[24]), "=&v"(DV[25]), "=&v"(DV[26]), "=&v"(DV[27]),         \
        "=&v"(DV[28]), "=&v"(DV[29]), "=&v"(DV[30]), "=&v"(DV[31])          \
      : "v"(ADDR)                                                           \
      : "memory")

#define SOFTMIN_STEP(DVK)                                                   \
  {                                                                         \
    const float up1 = dpp_shr1_old(B, ra);                                  \
    B = dpp_shl1(B);                                                        \
    const float m = fminf(fminf(up1, up2), ra);                             \
    const float md = __builtin_amdgcn_fmed3f(up1, up2, ra);                 \
    const float mx = fmaxf(fmaxf(up1, up2), ra);                            \
    const float ssum = (fexp2(m - md) + fexp2(m - mx)) + 1.0f;              \
    n = ((DVK) + m) - flog2(ssum);                                          \
    up2 = up1;                                                              \
  }

// ---------------- Kernel 2: soft-DTW wavefront DP (base-2 domain) ----------
// One block per batch, 8 waves x 64 lanes, 1 row per lane (2 waves/SIMD).
// CSPAN=64 halves the barrier-phase count (39 -> 23) to test whether the
// invariant ~6.5k cy/phase is per-phase fixed overhead (A/B vs round 11).
// Single D-buffer per block: DMA for span c+1 is issued only after the
// mega-asm's lgkmcnt(0) retires all span-c reads (no overwrite race);
// vmcnt(0) gates consumption at the next phase with a full phase to hide.
extern __shared__ float smem[];
__global__ __launch_bounds__(512) void softdtw_kernel(
    const float* __restrict__ Dsk, float* __restrict__ out) {
  const int b = blockIdx.x;
  const int t = threadIdx.x;
  const int wu = __builtin_amdgcn_readfirstlane(t >> 6);
  const int lane = t & 63;
  const int blk = ((wu & 3) << 1) | (wu >> 2);  // row-block 0..7

  float* bufD = smem;                // [8][64][64]
  float* bbuf = smem + BUFD_FLOATS;  // [8][640]: row w col j at [w][62+j]

  for (int k = t; k < BBUF_FLOATS; k += 512) bbuf[k] = BIGF;
  __syncthreads();

  const float* __restrict__ Dskb = Dsk + (size_t)b * DIAGELEMS;

  // pre-issue DMA for this block's first span (c = blk)
  dma_span(Dskb, bufD, blk, blk, lane);

  const int r = 64 * blk + lane;  // 0-based row; cell row i = r+1
  float ra = BIGF;                // R'[i][j-1]
  // up2 = R'[i-1][j-1] = previous step's up1; seed R'[0][0]=0 for the origin.
  float up2 = (blk == 0 && lane == 0) ? 0.0f : BIGF;

  for (int S = 0; S < TPH; ++S) {
    const int cc = S - OFF * blk;  // phase-local span index
    if (cc >= 0 && cc < SPW) {
      const int c = cc + blk;  // global span (<= 15)
      // span-c DMA (issued last phase, or pre-loop) must have landed
      asm volatile("s_waitcnt vmcnt(0)" ::: "memory");

      // boundary stream: B[lane] = R'[64blk][64cc+1+lane]; step k consumes
      // B-orig[k] via lane0 of the dpp old-operand.
      float B = BIGF;
      if (blk) B = bbuf[blk * BBSTRIDE + 62 + 64 * cc + 1 + lane];

      const float* myD = bufD + blk * (CSPAN * 64);
      const __attribute__((address_space(3))) float* mp =
          (const __attribute__((address_space(3))) float*)(myD + lane);
      unsigned maddr = (unsigned)(size_t)mp;

      float dvlo[32], dvhi[32];
      DS_READ32(dvlo, maddr, "s_nop 0");
      DS_READ32(dvhi, maddr + 8192, "s_waitcnt lgkmcnt(0)");

      // prefetch next span into the SAME buffer — safe: all reads retired
      if (cc + 1 < SPW) dma_span(Dskb, bufD, blk, c + 1, lane);

      // unmasked publish target: column jv(k) = 64c - r + 1 + k.
      // Lane 63 (true boundary row 64(blk+1)) is provably the LAST writer
      // of every column the next block consumes; blk 7 dumps to row 0.
      float* pubp =
          bbuf + ((blk + 1) & 7) * BBSTRIDE + (62 + 64 * c - r + 1);

      float n;
      if (cc >= 1 && cc <= 7) {  // all 64 lanes active at all 64 steps
#pragma unroll
        for (int k = 0; k < CSPAN; ++k) {
          const float dval = (k < 32) ? dvlo[k] : dvhi[k - 32];
          SOFTMIN_STEP(dval);
          ra = n;
          pubp[k] = ra;
        }
      } else {  // edge phases (cc == 0 or 8): keep activity mask
        const int jv0 = 64 * c - r + 1;
#pragma unroll
        for (int k = 0; k < CSPAN; ++k) {
          const float dval = (k < 32) ? dvlo[k] : dvhi[k - 32];
          SOFTMIN_STEP(dval);
          const bool a0 = (unsigned)(jv0 + k - 1) < (unsigned)MM;
          ra = a0 ? n : ra;
          pubp[k] = ra;
        }
      }
    }
    // Raw barrier: drain LDS ops only (publish visibility); DMA prefetch
    // stays in flight across the barrier (vmcnt-gated at its consumer).
    asm volatile("s_waitcnt lgkmcnt(0)" ::: "memory");
    __builtin_amdgcn_s_barrier();
  }

  if (blk == WAVES - 1 && lane == 63) out[b] = ra * LN2F;  // R'[512][512]
}

extern "C" void kernel_launch(void* const* d_in, const int* in_sizes, int n_in,
                              void* d_out, int out_size, void* d_ws,
                              size_t ws_size, hipStream_t stream) {
  const float* X = (const float*)d_in[0];
  const float* Y = (const float*)d_in[1];
  float* out = (float*)d_out;
  float* Dsk = (float*)d_ws;

  const size_t needed = (size_t)NB * DIAGELEMS * sizeof(float);
  if (ws_size < needed) return;

  hipFuncSetAttribute((const void*)softdtw_kernel,
                      hipFuncAttributeMaxDynamicSharedMemorySize, SMEM_BYTES);

  pairdist_kernel<<<dim3(MM / 64, NN / 64, NB), 256, 0, stream>>>(X, Y, Dsk);
  softdtw_kernel<<<NB, 512, SMEM_BYTES, stream>>>(Dsk, out);
}